// Round 5
// baseline (234.362 us; speedup 1.0000x reference)
//
#include <hip/hip_runtime.h>

// LoRA linear, fp32 in/out: out = x @ (W + 2*B@A)^T + b
//   prep: Weff = bf16(W + 2*B@A) (2 MiB ws)  +  xbf = bf16(x) (32 MiB ws)
//   gemm: LDS-FREE 128x128 bf16 MFMA GEMM. Fragments loaded directly from
//         global (A/B operand layout == row-major 16B/lane), Weff is
//         L2-resident (2 MiB), x-major dispatch keeps an m-slab's 8 n-blocks
//         on one XCD. NO barrier in K-loop -> register-level 1-deep pipeline
//         with compiler fine-grained vmcnt (the AITER pattern; R4 proved the
//         LDS+barrier structure caps at 22% MfmaUtil regardless of dbuf).

typedef __bf16 bf16x8 __attribute__((ext_vector_type(8)));
typedef float f32x4 __attribute__((ext_vector_type(4)));
typedef unsigned short ushort8 __attribute__((ext_vector_type(8)));  // 16B

__device__ __forceinline__ unsigned short f2bf(float f) {
    union { __bf16 b; unsigned short u; } v; v.b = (__bf16)f; return v.u;
}
__device__ __forceinline__ ushort8 cvt8(f32x4 a, f32x4 b) {
    ushort8 o;
#pragma unroll
    for (int i = 0; i < 4; ++i) { o[i] = f2bf(a[i]); o[i + 4] = f2bf(b[i]); }
    return o;
}
__device__ __forceinline__ bf16x8 cvtfrag(f32x4 a, f32x4 b) {
    union { ushort8 u; bf16x8 h; } v; v.u = cvt8(a, b); return v.h;
}

// ---------------- prep ----------------
__global__ __launch_bounds__(256) void prep(
    const float* __restrict__ X, const float* __restrict__ W,
    const float* __restrict__ A, const float* __restrict__ B,
    unsigned short* __restrict__ xbf, unsigned short* __restrict__ Weff)
{
    const int b = blockIdx.x;
    if (b < 512) {
        const int idx = b * 256 + threadIdx.x;
        const int o  = idx >> 7;
        const int kc = (idx & 127) << 3;
        float br[16];
#pragma unroll
        for (int r = 0; r < 16; ++r) br[r] = 2.0f * B[o * 16 + r];
        float acc[8];
        const float* wrow = W + (size_t)o * 1024 + kc;
#pragma unroll
        for (int j = 0; j < 8; ++j) acc[j] = wrow[j];
#pragma unroll
        for (int r = 0; r < 16; ++r) {
            const float* arow = A + r * 1024 + kc;
#pragma unroll
            for (int j = 0; j < 8; ++j) acc[j] += br[r] * arow[j];
        }
        ushort8 o8;
#pragma unroll
        for (int j = 0; j < 8; ++j) o8[j] = f2bf(acc[j]);
        *(ushort8*)(Weff + (size_t)o * 1024 + kc) = o8;
    } else {
        const size_t i = ((size_t)(b - 512) * 256 + threadIdx.x) * 8;
        f32x4 a = *(const f32x4*)(X + i);
        f32x4 c = *(const f32x4*)(X + i + 4);
        *(ushort8*)(xbf + i) = cvt8(a, c);
    }
}

// ---------------- gemm: LDS-free, barrier-free K-loop ----------------
// 256 thr = 4 waves, each a 64x64 quadrant (4x4 of 16x16x32 MFMA).
// Fragment source: lane reads 16B at row (tile_row + lane&15), col kt + (lane>>4)*8
// -> a wave's load = 16 rows x 64B fully-used segments.
template <bool XF32>
__global__ __launch_bounds__(256) void gemm_direct(
    const void* __restrict__ X_,               // bf16 [M][1024] (fp32 in fallback)
    const unsigned short* __restrict__ Wt,     // bf16 Weff [1024][1024]
    const float* __restrict__ bias,            // fp32 [1024]
    float* __restrict__ out)                   // fp32 [M][1024]
{
    const int t    = threadIdx.x;
    const int lane = t & 63;
    const int w    = t >> 6;
    const int bm   = blockIdx.x * 128;
    const int bn   = blockIdx.y * 128;
    const int wm   = (w & 1) * 64;
    const int wn   = (w >> 1) * 64;
    const int r16  = lane & 15;
    const int quad = lane >> 4;

    const unsigned short* Xb = (const unsigned short*)X_;
    const float*          Xf = (const float*)X_;

    // per-thread row base pointers (fragment layout: k = quad*8 + j)
    const unsigned short* rowA[4];
    const float*          rowAf[4];
    const unsigned short* rowB[4];
#pragma unroll
    for (int mt = 0; mt < 4; ++mt) {
        const size_t r = (size_t)(bm + wm + mt * 16 + r16) * 1024 + quad * 8;
        rowA[mt]  = Xb + r;
        rowAf[mt] = Xf + r;
    }
#pragma unroll
    for (int nt = 0; nt < 4; ++nt)
        rowB[nt] = Wt + (size_t)(bn + wn + nt * 16 + r16) * 1024 + quad * 8;

    f32x4 acc[4][4];
#pragma unroll
    for (int i = 0; i < 4; ++i)
#pragma unroll
        for (int j = 0; j < 4; ++j) {
            f32x4 z = {0.f, 0.f, 0.f, 0.f};
            acc[i][j] = z;
        }

    // 1-deep register pipeline: cur fragments in (fa,fb), prefetch into (na,nb)
    bf16x8 fa[4], fb[4], na[4], nb[4];
#pragma unroll
    for (int mt = 0; mt < 4; ++mt)
        fa[mt] = XF32 ? cvtfrag(*(const f32x4*)(rowAf[mt]),
                                *(const f32x4*)(rowAf[mt] + 4))
                      : *(const bf16x8*)(rowA[mt]);
#pragma unroll
    for (int nt = 0; nt < 4; ++nt) fb[nt] = *(const bf16x8*)(rowB[nt]);

    for (int kt = 0; kt < 1024; kt += 32) {
        const int kn = kt + 32;
        if (kn < 1024) {  // issue next-tile loads; no barrier -> overlaps MFMA below
#pragma unroll
            for (int mt = 0; mt < 4; ++mt)
                na[mt] = XF32 ? cvtfrag(*(const f32x4*)(rowAf[mt] + kn),
                                        *(const f32x4*)(rowAf[mt] + kn + 4))
                              : *(const bf16x8*)(rowA[mt] + kn);
#pragma unroll
            for (int nt = 0; nt < 4; ++nt) nb[nt] = *(const bf16x8*)(rowB[nt] + kn);
        }

#pragma unroll
        for (int mt = 0; mt < 4; ++mt)
#pragma unroll
            for (int nt = 0; nt < 4; ++nt)
                acc[mt][nt] = __builtin_amdgcn_mfma_f32_16x16x32_bf16(
                    fa[mt], fb[nt], acc[mt][nt], 0, 0, 0);

#pragma unroll
        for (int mt = 0; mt < 4; ++mt) fa[mt] = na[mt];
#pragma unroll
        for (int nt = 0; nt < 4; ++nt) fb[nt] = nb[nt];
    }

    // epilogue: C/D layout col=lane&15, row=quad*4+reg (verified R2-R4)
    const int orow0 = bm + wm + quad * 4;
    const int ocol0 = bn + wn + r16;
#pragma unroll
    for (int nt = 0; nt < 4; ++nt) {
        const float bv = bias[ocol0 + nt * 16];
#pragma unroll
        for (int mt = 0; mt < 4; ++mt)
#pragma unroll
            for (int i = 0; i < 4; ++i)
                out[(size_t)(orow0 + mt * 16 + i) * 1024 + (ocol0 + nt * 16)] =
                    acc[mt][nt][i] + bv;
    }
}

extern "C" void kernel_launch(void* const* d_in, const int* in_sizes, int n_in,
                              void* d_out, int out_size, void* d_ws, size_t ws_size,
                              hipStream_t stream) {
    const float* x  = (const float*)d_in[0];   // [M][1024]
    const float* W  = (const float*)d_in[1];   // [1024][1024]
    const float* b  = (const float*)d_in[2];   // [1024]
    const float* A  = (const float*)d_in[3];   // [16][1024]
    const float* Bm = (const float*)d_in[4];   // [1024][16]
    float* out = (float*)d_out;

    const int M = in_sizes[0] / 1024;          // 16384
    dim3 grid(M / 128, 1024 / 128);            // x-major: 8 n-blocks/m-slab -> same XCD

    const bool fast = ws_size >= ((size_t)(M)*1024*2 + (2u << 20) + 4096);
    if (fast) {
        unsigned short* xbf  = (unsigned short*)d_ws;
        unsigned short* Weff = xbf + (size_t)M * 1024;
        hipLaunchKernelGGL(prep, dim3(512 + M / 2), dim3(256), 0, stream,
                           x, W, A, Bm, xbf, Weff);
        hipLaunchKernelGGL((gemm_direct<false>), grid, dim3(256), 0, stream,
                           (const void*)xbf, Weff, b, out);
    } else {
        unsigned short* Weff = (unsigned short*)d_ws;
        hipLaunchKernelGGL(prep, dim3(512), dim3(256), 0, stream,
                           x, W, A, Bm, (unsigned short*)nullptr, Weff);
        hipLaunchKernelGGL((gemm_direct<true>), grid, dim3(256), 0, stream,
                           (const void*)x, Weff, b, out);
    }
}

// Round 6
// 174.393 us; speedup vs baseline: 1.3439x; 1.3439x over previous
//
#include <hip/hip_runtime.h>

// LoRA linear, fp32 in/out: out = x @ (W + 2*B@A)^T + b
//   prep: Weff = bf16(W + 2*B@A) (2 MiB ws)  +  xbf = bf16(x) (32 MiB ws)
//   gemm: 64x64 tiles, SINGLE-WAVE workgroups (4096 blocks = 16 stall
//         domains/CU; __syncthreads in a 1-wave block is a wave-local
//         waitcnt, no cross-wave rendezvous). global_load_lds w=16 staging,
//         XOR k-chunk swizzle (0 conflicts, R3-verified). R5 proved
//         register-ILP can't hide 900-cyc HBM latency; R3/R4 proved 4
//         block-granular stall domains aren't enough -> go to 16 wave-
//         granular domains. Per-CU MFMA busy is only ~4 us; HBM floor ~16 us.

typedef __bf16 bf16x8 __attribute__((ext_vector_type(8)));
typedef float f32x4 __attribute__((ext_vector_type(4)));
typedef unsigned short ushort8 __attribute__((ext_vector_type(8)));  // 16B

__device__ __forceinline__ unsigned short f2bf(float f) {
    union { __bf16 b; unsigned short u; } v; v.b = (__bf16)f; return v.u;
}
__device__ __forceinline__ ushort8 cvt8(f32x4 a, f32x4 b) {
    ushort8 o;
#pragma unroll
    for (int i = 0; i < 4; ++i) { o[i] = f2bf(a[i]); o[i + 4] = f2bf(b[i]); }
    return o;
}
__device__ __forceinline__ void gld16(const unsigned short* g, unsigned short* l) {
    __builtin_amdgcn_global_load_lds(
        (const __attribute__((address_space(1))) unsigned int*)g,
        (__attribute__((address_space(3))) unsigned int*)l, 16, 0, 0);
}

// ---------------- prep ----------------
__global__ __launch_bounds__(256) void prep(
    const float* __restrict__ X, const float* __restrict__ W,
    const float* __restrict__ A, const float* __restrict__ B,
    unsigned short* __restrict__ xbf, unsigned short* __restrict__ Weff)
{
    const int b = blockIdx.x;
    if (b < 512) {
        const int idx = b * 256 + threadIdx.x;
        const int o  = idx >> 7;
        const int kc = (idx & 127) << 3;
        float br[16];
#pragma unroll
        for (int r = 0; r < 16; ++r) br[r] = 2.0f * B[o * 16 + r];
        float acc[8];
        const float* wrow = W + (size_t)o * 1024 + kc;
#pragma unroll
        for (int j = 0; j < 8; ++j) acc[j] = wrow[j];
#pragma unroll
        for (int r = 0; r < 16; ++r) {
            const float* arow = A + r * 1024 + kc;
#pragma unroll
            for (int j = 0; j < 8; ++j) acc[j] += br[r] * arow[j];
        }
        ushort8 o8;
#pragma unroll
        for (int j = 0; j < 8; ++j) o8[j] = f2bf(acc[j]);
        *(ushort8*)(Weff + (size_t)o * 1024 + kc) = o8;
    } else {
        const size_t i = ((size_t)(b - 512) * 256 + threadIdx.x) * 8;
        f32x4 a = *(const f32x4*)(X + i);
        f32x4 c = *(const f32x4*)(X + i + 4);
        *(ushort8*)(xbf + i) = cvt8(a, c);
    }
}

// ---------------- gemm: 64x64 tile, one wave per block ----------------
// Wave computes 4x4 of 16x16x32 MFMA. LDS [64][32] bf16 per operand (8 KB).
// Staging instr j (j=0..3): lane l -> row j*16 + (l>>2), phys k-chunk l&3,
// global k-chunk gc = (l&3) ^ (((l>>2)>>1)&3)  (j*16 doesn't affect bits 1..2
// of row>>1 mod 4, so gc is j-invariant). Reader un-swizzles with the same
// formula -> 2-way-max bank aliasing (free), verified 0 conflicts in R3.
template <bool XF32>
__global__ __launch_bounds__(64, 4) void gemm_w64(
    const void* __restrict__ X_,               // bf16 [M][1024] (fp32 fallback)
    const unsigned short* __restrict__ Wt,     // bf16 Weff [1024][1024]
    const float* __restrict__ bias,            // fp32 [1024]
    float* __restrict__ out)                   // fp32 [M][1024]
{
    __shared__ __align__(16) unsigned short lA[64 * 32];
    __shared__ __align__(16) unsigned short lB[64 * 32];

    const int lane = threadIdx.x;
    const int bm   = blockIdx.x * 64;
    const int bn   = blockIdx.y * 64;
    const int r16  = lane & 15;
    const int quad = lane >> 4;
    const int sr   = lane >> 2;                    // sub-row 0..15
    const int gc   = (lane & 3) ^ ((sr >> 1) & 3); // swizzled global k-chunk

    const unsigned short* Xb = (const unsigned short*)X_;
    const float*          Xf = (const float*)X_;

    size_t gA[4], gB[4];
#pragma unroll
    for (int j = 0; j < 4; ++j) {
        gA[j] = (size_t)(bm + j * 16 + sr) * 1024 + gc * 8;
        gB[j] = (size_t)(bn + j * 16 + sr) * 1024 + gc * 8;
    }
    unsigned short* const lsA = lA + lane * 8;     // 16B slot, instr j at +j*512
    unsigned short* const lsB = lB + lane * 8;

    // reader: logical chunk quad lives at physical slot quad ^ ((r16>>1)&3)
    const int p    = (quad ^ ((r16 >> 1) & 3)) * 8;
    const int aoff = r16 * 32 + p;                 // + mt*16*32

    f32x4 acc[4][4];
#pragma unroll
    for (int i = 0; i < 4; ++i)
#pragma unroll
        for (int j = 0; j < 4; ++j) {
            f32x4 z = {0.f, 0.f, 0.f, 0.f};
            acc[i][j] = z;
        }

    for (int kt = 0; kt < 1024; kt += 32) {
        if (XF32) {
#pragma unroll
            for (int j = 0; j < 4; ++j) {
                f32x4 a0 = *(const f32x4*)(Xf + gA[j] + kt);
                f32x4 a1 = *(const f32x4*)(Xf + gA[j] + kt + 4);
                *(ushort8*)(lsA + j * 512) = cvt8(a0, a1);
                gld16(Wt + gB[j] + kt, lsB + j * 512);
            }
        } else {
#pragma unroll
            for (int j = 0; j < 4; ++j) {
                gld16(Xb + gA[j] + kt, lsA + j * 512);
                gld16(Wt + gB[j] + kt, lsB + j * 512);
            }
        }
        __syncthreads();   // 1-wave block: wave-local waitcnt, no rendezvous

        bf16x8 fa[4], fb[4];
#pragma unroll
        for (int mt = 0; mt < 4; ++mt) fa[mt] = *(const bf16x8*)(lA + aoff + mt * 16 * 32);
#pragma unroll
        for (int nt = 0; nt < 4; ++nt) fb[nt] = *(const bf16x8*)(lB + aoff - (r16*32+p) + (bn*0) + (nt * 16 + r16) * 32 + p);

#pragma unroll
        for (int mt = 0; mt < 4; ++mt)
#pragma unroll
            for (int nt = 0; nt < 4; ++nt)
                acc[mt][nt] = __builtin_amdgcn_mfma_f32_16x16x32_bf16(
                    fa[mt], fb[nt], acc[mt][nt], 0, 0, 0);

        __syncthreads();   // protect LDS from next iter's overwrite (wave-local)
    }

    // epilogue: C/D layout col=lane&15, row=quad*4+reg (verified R2-R5)
    const int orow0 = bm + quad * 4;
    const int ocol0 = bn + r16;
#pragma unroll
    for (int nt = 0; nt < 4; ++nt) {
        const float bv = bias[ocol0 + nt * 16];
#pragma unroll
        for (int mt = 0; mt < 4; ++mt)
#pragma unroll
            for (int i = 0; i < 4; ++i)
                out[(size_t)(orow0 + mt * 16 + i) * 1024 + (ocol0 + nt * 16)] =
                    acc[mt][nt][i] + bv;
    }
}

extern "C" void kernel_launch(void* const* d_in, const int* in_sizes, int n_in,
                              void* d_out, int out_size, void* d_ws, size_t ws_size,
                              hipStream_t stream) {
    const float* x  = (const float*)d_in[0];   // [M][1024]
    const float* W  = (const float*)d_in[1];   // [1024][1024]
    const float* b  = (const float*)d_in[2];   // [1024]
    const float* A  = (const float*)d_in[3];   // [16][1024]
    const float* Bm = (const float*)d_in[4];   // [1024][16]
    float* out = (float*)d_out;

    const int M = in_sizes[0] / 1024;          // 16384
    dim3 grid(M / 64, 1024 / 64);              // 256 x 16 = 4096 blocks

    const bool fast = ws_size >= ((size_t)(M)*1024*2 + (2u << 20) + 4096);
    if (fast) {
        unsigned short* xbf  = (unsigned short*)d_ws;
        unsigned short* Weff = xbf + (size_t)M * 1024;
        hipLaunchKernelGGL(prep, dim3(512 + M / 2), dim3(256), 0, stream,
                           x, W, A, Bm, xbf, Weff);
        hipLaunchKernelGGL((gemm_w64<false>), grid, dim3(64), 0, stream,
                           (const void*)xbf, Weff, b, out);
    } else {
        unsigned short* Weff = (unsigned short*)d_ws;
        hipLaunchKernelGGL(prep, dim3(512), dim3(256), 0, stream,
                           x, W, A, Bm, (unsigned short*)nullptr, Weff);
        hipLaunchKernelGGL((gemm_w64<true>), grid, dim3(64), 0, stream,
                           (const void*)x, Weff, b, out);
    }
}